// Round 4
// baseline (1399.222 us; speedup 1.0000x reference)
//
#include <hip/hip_runtime.h>
#include <cmath>
#include <cstdint>

#define M_TOTAL 4096
#define K_DIM   2048
#define V_DIM   50257
#define V_PAD   50432            /* 197*256, zero-padded rows in converted W */
#define NVB     197              /* vocab blocks of 256 */
#define BM 128                   /* m rows per block */
#define BN 256                   /* vocab cols per block */
#define BK 32
#define NKT (K_DIM / BK)         /* 64 */
#define NWG (NVB * 32)           /* 6304 blocks; 6304/8 = 788 exact */
#define IGNORE_IDX (-100)
#define Z_REG 1e-4f

typedef __bf16 bf16_t;
typedef bf16_t bf16x8 __attribute__((ext_vector_type(8)));
typedef bf16_t bf16x4 __attribute__((ext_vector_type(4)));
typedef float  f32x4  __attribute__((ext_vector_type(4)));

typedef const __attribute__((address_space(1))) void g_cvoid;
typedef __attribute__((address_space(3))) void l_void;

// async global->LDS, 16B per lane; LDS dest = wave-uniform base + lane*16
__device__ __forceinline__ void gll16(const void* g, void* l) {
    __builtin_amdgcn_global_load_lds((g_cvoid*)(uintptr_t)g,
                                     (l_void*)(uint32_t)(uintptr_t)l, 16, 0, 0);
}

__device__ inline bf16x4 cvt4(f32x4 v) {
    bf16x4 r;
    r.x = (bf16_t)v.x; r.y = (bf16_t)v.y; r.z = (bf16_t)v.z; r.w = (bf16_t)v.w;
    return r;
}

// ---------------- fp32 -> bf16 convert (pads rows >= valid8 with zeros) ----
__global__ __launch_bounds__(256)
void cvt_f32_bf16(const float* __restrict__ src, bf16_t* __restrict__ dst,
                  long long total8, long long valid8)
{
    const long long stride = (long long)gridDim.x * 256;
    for (long long i = (long long)blockIdx.x * 256 + threadIdx.x; i < total8; i += stride) {
        bf16x8 o;
        if (i < valid8) {
            const float* s = src + i * 8;
            const f32x4 a = *(const f32x4*)s;
            const f32x4 b = *(const f32x4*)(s + 4);
            o[0]=(bf16_t)a.x; o[1]=(bf16_t)a.y; o[2]=(bf16_t)a.z; o[3]=(bf16_t)a.w;
            o[4]=(bf16_t)b.x; o[5]=(bf16_t)b.y; o[6]=(bf16_t)b.z; o[7]=(bf16_t)b.w;
        } else {
            #pragma unroll
            for (int z = 0; z < 8; ++z) o[z] = (bf16_t)0.f;
        }
        *(bf16x8*)(dst + i * 8) = o;
    }
}

// ---------------- pipelined fused GEMM + online softmax stats --------------
// 128x256 tile, BK=32, ring-4 LDS, fragment double-buffer in registers:
// per K-tile: {STAGE(t+3); ds_read frags(t+1); [lgkmcnt(8)]; MFMA(t);
//              vmcnt(3); barrier} — reads drain UNDER the MFMA cluster,
// one barrier per K-tile, vmcnt never drains to 0 mid-loop.
__global__ __launch_bounds__(512, 2)
void lce_gemm_pipe(const bf16_t* __restrict__ Xb, const bf16_t* __restrict__ Wb,
                   float* __restrict__ pm, float* __restrict__ ps)
{
    __shared__ __align__(16) bf16_t As[4][BM * BK];   // 4 x 8KB  = 32KB
    __shared__ __align__(16) bf16_t Bs[4][BN * BK];   // 4 x 16KB = 64KB

    const int bid = blockIdx.x;
    const int wg  = (bid & 7) * (NWG / 8) + (bid >> 3);   // XCD swizzle, bijective
    const int vb  = wg >> 5;        // m-inner: 32 consecutive wgs share one W panel
    const int mb  = wg & 31;
    const int m0  = mb * BM;
    const int v0  = vb * BN;

    const int tid  = threadIdx.x;
    const int lane = tid & 63;
    const int wave = tid >> 6;
    const int wr   = wave >> 2;     // 2(m) x 4(v) wave grid; per-wave 64x64 output
    const int wc   = wave & 3;
    const int lo4  = lane & 15;
    const int hi2  = lane >> 4;

    // read-side swizzle: row r stores global 16B-slot g at slot g^((r>>1)&3).
    // frag rows = R0 + lo4 (R0 % 16 == 0) -> xor term = (lo4>>1)&3.
    const int rswz = (hi2 ^ ((lo4 >> 1) & 3)) << 4;
    const int aoff = (wr * 64 + lo4) * 64 + rswz;
    const int boff = (wc * 64 + lo4) * 64 + rswz;

    // staging: lane l writes LDS linear (row = seg*16 + (l>>2), slot_lin = l&3);
    // inverse swizzle on the GLOBAL source: col-slot = (l&3) ^ ((l>>3)&3).
    const int srow = wave * 16 + (lane >> 2);              // 0..127
    const int scol = ((lane & 3) ^ ((lane >> 3) & 3)) << 3;
    const bf16_t* baseA = Xb + (size_t)(m0 + srow) * K_DIM + scol;
    const bf16_t* baseB = Wb + (size_t)(v0 + srow) * K_DIM + scol;
    char* ldsA_w = (char*)&As[0][0] + wave * 1024;
    char* ldsB_w = (char*)&Bs[0][0] + wave * 1024;
    const size_t U1B = (size_t)128 * K_DIM;                // B rows 128..255

#define STAGE(tt) do { const int _s = (tt) & 3;                          \
        gll16(baseA + (size_t)(tt) * BK,       ldsA_w + _s * 8192);      \
        gll16(baseB + (size_t)(tt) * BK,       ldsB_w + _s * 16384);     \
        gll16(baseB + (size_t)(tt) * BK + U1B, ldsB_w + _s * 16384 + 8192); \
    } while (0)

#define LDFRAG(af_, bv_, slot) do {                                      \
        const char* _Ab = (const char*)&As[0][0] + (slot) * 8192  + aoff;\
        const char* _Bb = (const char*)&Bs[0][0] + (slot) * 16384 + boff;\
        af_[0] = *(const bf16x8*)(_Ab);                                  \
        af_[1] = *(const bf16x8*)(_Ab + 1024);                           \
        af_[2] = *(const bf16x8*)(_Ab + 2048);                           \
        af_[3] = *(const bf16x8*)(_Ab + 3072);                           \
        bv_[0] = *(const bf16x8*)(_Bb);                                  \
        bv_[1] = *(const bf16x8*)(_Bb + 1024);                           \
        bv_[2] = *(const bf16x8*)(_Bb + 2048);                           \
        bv_[3] = *(const bf16x8*)(_Bb + 3072);                           \
    } while (0)

#define MFMA16(af_, bv_) do {                                            \
        _Pragma("unroll")                                                \
        for (int m = 0; m < 4; ++m)                                      \
            _Pragma("unroll")                                            \
            for (int n = 0; n < 4; ++n)                                  \
                acc[m][n] = __builtin_amdgcn_mfma_f32_16x16x32_bf16(     \
                    af_[m], bv_[n], acc[m][n], 0, 0, 0);                 \
    } while (0)

    f32x4 acc[4][4];
    #pragma unroll
    for (int m = 0; m < 4; ++m)
        #pragma unroll
        for (int n = 0; n < 4; ++n) {
            f32x4 z = {0.f, 0.f, 0.f, 0.f};
            acc[m][n] = z;
        }

    // prologue: stage tiles 0,1,2; ensure 0,1 landed (tile 2 stays in flight)
    STAGE(0); STAGE(1); STAGE(2);
    asm volatile("s_waitcnt vmcnt(3)" ::: "memory");
    __builtin_amdgcn_sched_barrier(0);
    __builtin_amdgcn_s_barrier();
    __builtin_amdgcn_sched_barrier(0);

    bf16x8 afE[4], bvE[4], afO[4], bvO[4];
    LDFRAG(afE, bvE, 0);

    for (int j = 0; j < NKT; j += 2) {
        // ---- even K-tile j: compute E, prefetch frags(j+1) -> O ----
        if (j + 3 < NKT) STAGE(j + 3);
        LDFRAG(afO, bvO, (j + 1) & 3);
        __builtin_amdgcn_s_setprio(1);
        MFMA16(afE, bvE);
        __builtin_amdgcn_s_setprio(0);
        if (j + 4 < NKT) asm volatile("s_waitcnt vmcnt(3)" ::: "memory");
        else             asm volatile("s_waitcnt vmcnt(0)" ::: "memory");
        __builtin_amdgcn_sched_barrier(0);
        __builtin_amdgcn_s_barrier();
        __builtin_amdgcn_sched_barrier(0);

        // ---- odd K-tile j+1: compute O, prefetch frags(j+2) -> E ----
        if (j + 4 < NKT) STAGE(j + 4);
        if (j + 2 < NKT) LDFRAG(afE, bvE, (j + 2) & 3);
        __builtin_amdgcn_s_setprio(1);
        MFMA16(afO, bvO);
        __builtin_amdgcn_s_setprio(0);
        if (j + 5 < NKT) asm volatile("s_waitcnt vmcnt(3)" ::: "memory");
        else             asm volatile("s_waitcnt vmcnt(0)" ::: "memory");
        __builtin_amdgcn_sched_barrier(0);
        __builtin_amdgcn_s_barrier();
        __builtin_amdgcn_sched_barrier(0);
    }
#undef STAGE
#undef LDFRAG
#undef MFMA16

    // ---- epilogue: per-row max/sumexp over this block's 256 cols ----------
    // C layout (m89): col = lane&15, row = (lane>>4)*4 + reg
    float* scrM = (float*)&As[0][0];     // [128][4] (2KB, slot-0 reuse: safe,
    float* scrS = scrM + 512;            //  slot 0's last read was tile 60)
    #pragma unroll
    for (int m = 0; m < 4; ++m) {
        #pragma unroll
        for (int jj = 0; jj < 4; ++jj) {
            float v_[4];
            float vmax = -INFINITY;
            #pragma unroll
            for (int n = 0; n < 4; ++n) {
                const int gcol = v0 + wc * 64 + n * 16 + lo4;
                const float v  = acc[m][n][jj];
                v_[n] = (gcol < V_DIM) ? v : -INFINITY;
                vmax = fmaxf(vmax, v_[n]);
            }
            #pragma unroll
            for (int d = 1; d < 16; d <<= 1)
                vmax = fmaxf(vmax, __shfl_xor(vmax, d, 64));
            float s = 0.f;
            if (vmax > -INFINITY) {      // uniform within 16-lane row group
                #pragma unroll
                for (int n = 0; n < 4; ++n) s += __expf(v_[n] - vmax);
                #pragma unroll
                for (int d = 1; d < 16; d <<= 1)
                    s += __shfl_xor(s, d, 64);
            }
            if (lo4 == 0) {
                const int row = wr * 64 + m * 16 + hi2 * 4 + jj;
                scrM[row * 4 + wc] = vmax;
                scrS[row * 4 + wc] = s;
            }
        }
    }
    __syncthreads();
    if (tid < BM) {
        float M = -INFINITY;
        #pragma unroll
        for (int w4 = 0; w4 < 4; ++w4) M = fmaxf(M, scrM[tid * 4 + w4]);
        float S = 0.f;
        #pragma unroll
        for (int w4 = 0; w4 < 4; ++w4) {
            const float mm = scrM[tid * 4 + w4];
            if (mm > -INFINITY) S += scrS[tid * 4 + w4] * __expf(mm - M);
        }
        const size_t idx = (size_t)vb * M_TOTAL + m0 + tid;
        pm[idx] = M;
        ps[idx] = S;
    }
}

// ---------------- picked logit: one wave per row ---------------------------
__global__ __launch_bounds__(256)
void lce_picked(const bf16_t* __restrict__ Xb, const bf16_t* __restrict__ Wb,
                const int* __restrict__ labels, float* __restrict__ picked)
{
    const int wv  = threadIdx.x >> 6, ln = threadIdx.x & 63;
    const int row = blockIdx.x * 4 + wv;
    const int lbl = labels[row];
    float s = 0.f;
    if (lbl != IGNORE_IDX) {
        const bf16_t* xr = Xb + (size_t)row * K_DIM;
        const bf16_t* wr = Wb + (size_t)lbl * K_DIM;
        #pragma unroll
        for (int c = 0; c < 4; ++c) {
            const bf16x8 a = *(const bf16x8*)(xr + c * 512 + ln * 8);
            const bf16x8 b = *(const bf16x8*)(wr + c * 512 + ln * 8);
            #pragma unroll
            for (int i = 0; i < 8; ++i) s += (float)a[i] * (float)b[i];
        }
    }
    #pragma unroll
    for (int d = 32; d; d >>= 1) s += __shfl_down(s, d, 64);
    if (ln == 0) picked[row] = s;
}

// ---------------- chunk-combine + finalize ---------------------------------
__global__ __launch_bounds__(256)
void lce_row_reduce(const float* __restrict__ pm, const float* __restrict__ ps,
                    const float* __restrict__ picked, const int* __restrict__ labels,
                    float* __restrict__ pb)
{
    const int r   = blockIdx.x * 256 + threadIdx.x;
    const int lbl = labels[r];
    float nll = 0.f, zsq = 0.f, val = 0.f;
    if (lbl != IGNORE_IDX) {
        float M = -INFINITY;
        for (int c = 0; c < NVB; ++c)
            M = fmaxf(M, pm[(size_t)c * M_TOTAL + r]);
        float S = 0.f;
        for (int c = 0; c < NVB; ++c) {
            const float mc = pm[(size_t)c * M_TOTAL + r];
            if (mc > -INFINITY) S += ps[(size_t)c * M_TOTAL + r] * expf(mc - M);
        }
        const float lse = M + logf(S);
        nll = lse - picked[r];
        zsq = lse * lse;
        val = 1.f;
    }
    #pragma unroll
    for (int d = 32; d; d >>= 1) {
        nll += __shfl_down(nll, d, 64);
        zsq += __shfl_down(zsq, d, 64);
        val += __shfl_down(val, d, 64);
    }
    __shared__ float red[3][4];
    const int wv = threadIdx.x >> 6, ln = threadIdx.x & 63;
    if (ln == 0) { red[0][wv] = nll; red[1][wv] = zsq; red[2][wv] = val; }
    __syncthreads();
    if (threadIdx.x == 0) {
        float a = 0.f, b = 0.f, c_ = 0.f;
        #pragma unroll
        for (int i = 0; i < 4; ++i) { a += red[0][i]; b += red[1][i]; c_ += red[2][i]; }
        pb[blockIdx.x * 3 + 0] = a;
        pb[blockIdx.x * 3 + 1] = b;
        pb[blockIdx.x * 3 + 2] = c_;
    }
}

__global__ void lce_finalize(const float* __restrict__ pb, float* __restrict__ out)
{
    float a = 0.f, b = 0.f, c_ = 0.f;
    for (int i = 0; i < 16; ++i) {
        a  += pb[i * 3 + 0];
        b  += pb[i * 3 + 1];
        c_ += pb[i * 3 + 2];
    }
    const float denom = fmaxf(c_, 1.f);
    float loss = a / denom;
    if (c_ > 0.f) loss += Z_REG * (b / denom);
    out[0] = loss;
}

// ---------------- fallback fused fp32 path (round-0 kernel, tiny ws) -------
#define FVC 1024
#define FNCHUNK 50
#define FBK 64
#define LDSPAD 72
__global__ __launch_bounds__(256)
void lce_gemm_stats_fused(const float* __restrict__ X, const float* __restrict__ W,
                          const int* __restrict__ labels,
                          float* __restrict__ pm, float* __restrict__ ps,
                          float* __restrict__ pp)
{
    __shared__ bf16_t As[128][LDSPAD];
    __shared__ bf16_t Bsh[128][LDSPAD];
    __shared__ float  sm[128], ss[128], sp[128];
    __shared__ float  part_m[2][128], part_s[2][128];
    __shared__ int    slab[128];

    const int bx    = blockIdx.x;
    const int chunk = bx >> 5;
    const int mb    = bx & 31;
    const int m0    = mb * 128;
    const int v0    = chunk * FVC;
    const int tid   = threadIdx.x;
    const int lane  = tid & 63;
    const int wave  = tid >> 6;
    const int wr    = wave >> 1;
    const int wc    = wave & 1;
    const int lo4   = lane & 15;
    const int hi2   = lane >> 4;
    const int sr0   = tid >> 4;
    const int sc4   = tid & 15;

    if (tid < 128) {
        sm[tid] = -INFINITY; ss[tid] = 0.f; sp[tid] = 0.f;
        slab[tid] = labels[m0 + tid];
    }
    __syncthreads();

    const int ncols = min(FVC, V_DIM - v0);
    const int nt    = (ncols + 127) >> 7;

    for (int vt = 0; vt < nt; ++vt) {
        f32x4 acc[4][4];
        #pragma unroll
        for (int m = 0; m < 4; ++m)
            #pragma unroll
            for (int n = 0; n < 4; ++n) {
                f32x4 z = {0.f, 0.f, 0.f, 0.f};
                acc[m][n] = z;
            }
        const int vrow0 = v0 + vt * 128;
        for (int kt = 0; kt < K_DIM / FBK; ++kt) {
            #pragma unroll
            for (int i = 0; i < 8; ++i) {
                const int row = i * 16 + sr0;
                const f32x4 va = *(const f32x4*)(X + (size_t)(m0 + row) * K_DIM + kt * FBK + sc4 * 4);
                *(bf16x4*)&As[row][sc4 * 4] = cvt4(va);
                const int grow = vrow0 + row;
                f32x4 vb = {0.f, 0.f, 0.f, 0.f};
                if (grow < V_DIM)
                    vb = *(const f32x4*)(W + (size_t)grow * K_DIM + kt * FBK + sc4 * 4);
                *(bf16x4*)&Bsh[row][sc4 * 4] = cvt4(vb);
            }
            __syncthreads();
            #pragma unroll
            for (int ks = 0; ks < 2; ++ks) {
                bf16x8 af[4], bfr[4];
                #pragma unroll
                for (int m = 0; m < 4; ++m)
                    af[m] = *(const bf16x8*)&As[wr * 64 + m * 16 + lo4][ks * 32 + hi2 * 8];
                #pragma unroll
                for (int n = 0; n < 4; ++n)
                    bfr[n] = *(const bf16x8*)&Bsh[wc * 64 + n * 16 + lo4][ks * 32 + hi2 * 8];
                #pragma unroll
                for (int m = 0; m < 4; ++m)
                    #pragma unroll
                    for (int n = 0; n < 4; ++n)
                        acc[m][n] = __builtin_amdgcn_mfma_f32_16x16x32_bf16(af[m], bfr[n], acc[m][n], 0, 0, 0);
            }
            __syncthreads();
        }
        const int vbase = vrow0 + wc * 64;
        #pragma unroll
        for (int m = 0; m < 4; ++m) {
            #pragma unroll
            for (int j = 0; j < 4; ++j) {
                const int rloc = wr * 64 + m * 16 + hi2 * 4 + j;
                const int lb   = slab[rloc];
                float vmax = -INFINITY;
                float v_[4];
                #pragma unroll
                for (int n = 0; n < 4; ++n) {
                    const int gcol = vbase + n * 16 + lo4;
                    const float v  = acc[m][n][j];
                    const bool ok  = (gcol < V_DIM);
                    v_[n] = ok ? v : -INFINITY;
                    if (ok && gcol == lb) sp[rloc] = v;
                    vmax = fmaxf(vmax, v_[n]);
                }
                #pragma unroll
                for (int d = 1; d < 16; d <<= 1)
                    vmax = fmaxf(vmax, __shfl_xor(vmax, d, 64));
                float s = 0.f;
                #pragma unroll
                for (int n = 0; n < 4; ++n) s += __expf(v_[n] - vmax);
                #pragma unroll
                for (int d = 1; d < 16; d <<= 1) s += __shfl_xor(s, d, 64);
                if (lo4 == 0) { part_m[wc][rloc] = vmax; part_s[wc][rloc] = s; }
            }
        }
        __syncthreads();
        if (tid < 128) {
            const float om  = sm[tid], os = ss[tid];
            const float m0_ = part_m[0][tid], s0 = part_s[0][tid];
            const float m1_ = part_m[1][tid], s1 = part_s[1][tid];
            const float nm  = fmaxf(om, fmaxf(m0_, m1_));
            float ns = 0.f;
            if (om  > -INFINITY) ns += os * __expf(om  - nm);
            if (m0_ > -INFINITY) ns += s0 * __expf(m0_ - nm);
            if (m1_ > -INFINITY) ns += s1 * __expf(m1_ - nm);
            sm[tid] = nm; ss[tid] = ns;
        }
    }
    __syncthreads();
    if (tid < 128) {
        const size_t idx = (size_t)chunk * M_TOTAL + (m0 + tid);
        pm[idx] = sm[tid]; ps[idx] = ss[tid]; pp[idx] = sp[tid];
    }
}

__global__ __launch_bounds__(256)
void lce_row_reduce_f(const float* __restrict__ pm, const float* __restrict__ ps,
                      const float* __restrict__ pp, const int* __restrict__ labels,
                      float* __restrict__ pb)
{
    const int r   = blockIdx.x * 256 + threadIdx.x;
    const int lbl = labels[r];
    float nll = 0.f, zsq = 0.f, val = 0.f;
    if (lbl != IGNORE_IDX) {
        float M = -INFINITY;
        for (int c = 0; c < FNCHUNK; ++c)
            M = fmaxf(M, pm[(size_t)c * M_TOTAL + r]);
        float S = 0.f, P = 0.f;
        for (int c = 0; c < FNCHUNK; ++c) {
            const float mc = pm[(size_t)c * M_TOTAL + r];
            if (mc > -INFINITY) S += ps[(size_t)c * M_TOTAL + r] * expf(mc - M);
            P += pp[(size_t)c * M_TOTAL + r];
        }
        const float lse = M + logf(S);
        nll = lse - P; zsq = lse * lse; val = 1.f;
    }
    #pragma unroll
    for (int d = 32; d; d >>= 1) {
        nll += __shfl_down(nll, d, 64);
        zsq += __shfl_down(zsq, d, 64);
        val += __shfl_down(val, d, 64);
    }
    __shared__ float red[3][4];
    const int wv = threadIdx.x >> 6, ln = threadIdx.x & 63;
    if (ln == 0) { red[0][wv] = nll; red[1][wv] = zsq; red[2][wv] = val; }
    __syncthreads();
    if (threadIdx.x == 0) {
        float a = 0.f, b = 0.f, c_ = 0.f;
        #pragma unroll
        for (int i = 0; i < 4; ++i) { a += red[0][i]; b += red[1][i]; c_ += red[2][i]; }
        pb[blockIdx.x * 3 + 0] = a;
        pb[blockIdx.x * 3 + 1] = b;
        pb[blockIdx.x * 3 + 2] = c_;
    }
}

extern "C" void kernel_launch(void* const* d_in, const int* in_sizes, int n_in,
                              void* d_out, int out_size, void* d_ws, size_t ws_size,
                              hipStream_t stream)
{
    const float* x      = (const float*)d_in[0];
    const int*   labels = (const int*)d_in[1];
    const float* w      = (const float*)d_in[2];
    float*       out    = (float*)d_out;

    const size_t wb_elems = (size_t)V_PAD * K_DIM;      // 103,284,736
    const size_t xb_elems = (size_t)M_TOTAL * K_DIM;    // 8,388,608
    const size_t stat_n   = (size_t)NVB * M_TOTAL;      // 806,912
    const size_t stat_off = wb_elems * 2 + xb_elems * 2;
    const size_t need     = stat_off + stat_n * 2 * sizeof(float)
                          + M_TOTAL * sizeof(float) + 16 * 3 * sizeof(float) + 256;

    if (ws_size >= need) {
        bf16_t* Wb     = (bf16_t*)d_ws;
        bf16_t* Xb     = Wb + wb_elems;
        float*  pm     = (float*)((char*)d_ws + stat_off);
        float*  ps     = pm + stat_n;
        float*  picked = ps + stat_n;
        float*  pb     = picked + M_TOTAL;

        cvt_f32_bf16<<<dim3(4096), dim3(256), 0, stream>>>(
            w, Wb, (long long)(wb_elems / 8), (long long)((size_t)V_DIM * K_DIM / 8));
        cvt_f32_bf16<<<dim3(1024), dim3(256), 0, stream>>>(
            x, Xb, (long long)(xb_elems / 8), (long long)(xb_elems / 8));
        lce_gemm_pipe<<<dim3(NWG), dim3(512), 0, stream>>>(Xb, Wb, pm, ps);
        lce_picked<<<dim3(1024), dim3(256), 0, stream>>>(Xb, Wb, labels, picked);
        lce_row_reduce<<<dim3(16), dim3(256), 0, stream>>>(pm, ps, picked, labels, pb);
        lce_finalize<<<dim3(1), dim3(1), 0, stream>>>(pb, out);
    } else {
        const size_t fstat_n = (size_t)FNCHUNK * M_TOTAL;
        float* pm = (float*)d_ws;
        float* ps = pm + fstat_n;
        float* pp = ps + fstat_n;
        float* pb = pp + fstat_n;
        lce_gemm_stats_fused<<<dim3(FNCHUNK * 32), dim3(256), 0, stream>>>(
            x, w, labels, pm, ps, pp);
        lce_row_reduce_f<<<dim3(16), dim3(256), 0, stream>>>(pm, ps, pp, labels, pb);
        lce_finalize<<<dim3(1), dim3(1), 0, stream>>>(pb, out);
    }
}

// Round 5
// 1095.445 us; speedup vs baseline: 1.2773x; 1.2773x over previous
//
#include <hip/hip_runtime.h>
#include <cmath>
#include <cstdint>

#define M_TOTAL 4096
#define K_DIM   2048
#define V_DIM   50257
#define V_PAD   50432            /* 197*256, zero-padded rows in converted W */
#define NVB     197              /* vocab blocks of 256 */
#define BM 256
#define BK 32
#define NKT (K_DIM / BK)         /* 64 */
#define NWG (NVB * 16)           /* 3152; 3152/8 = 394 exact */
#define IGNORE_IDX (-100)
#define Z_REG 1e-4f

typedef __bf16 bf16_t;
typedef bf16_t bf16x8 __attribute__((ext_vector_type(8)));
typedef bf16_t bf16x4 __attribute__((ext_vector_type(4)));
typedef float  f32x4  __attribute__((ext_vector_type(4)));

typedef const __attribute__((address_space(1))) void g_cvoid;
typedef __attribute__((address_space(3))) void l_void;

__device__ __forceinline__ void gll16(const void* g, void* l) {
    __builtin_amdgcn_global_load_lds((g_cvoid*)(uintptr_t)g,
                                     (l_void*)(uint32_t)(uintptr_t)l, 16, 0, 0);
}

__device__ inline bf16x4 cvt4(f32x4 v) {
    bf16x4 r;
    r.x = (bf16_t)v.x; r.y = (bf16_t)v.y; r.z = (bf16_t)v.z; r.w = (bf16_t)v.w;
    return r;
}

// ---------------- fp32 -> bf16 convert (pads rows >= valid8 with zeros) ----
__global__ __launch_bounds__(256)
void cvt_f32_bf16(const float* __restrict__ src, bf16_t* __restrict__ dst,
                  long long total8, long long valid8)
{
    const long long stride = (long long)gridDim.x * 256;
    for (long long i = (long long)blockIdx.x * 256 + threadIdx.x; i < total8; i += stride) {
        bf16x8 o;
        if (i < valid8) {
            const float* s = src + i * 8;
            const f32x4 a = *(const f32x4*)s;
            const f32x4 b = *(const f32x4*)(s + 4);
            o[0]=(bf16_t)a.x; o[1]=(bf16_t)a.y; o[2]=(bf16_t)a.z; o[3]=(bf16_t)a.w;
            o[4]=(bf16_t)b.x; o[5]=(bf16_t)b.y; o[6]=(bf16_t)b.z; o[7]=(bf16_t)b.w;
        } else {
            #pragma unroll
            for (int z = 0; z < 8; ++z) o[z] = (bf16_t)0.f;
        }
        *(bf16x8*)(dst + i * 8) = o;
    }
}

// ---------------- fused GEMM + online softmax stats ------------------------
// 256x256 tile, BK=32, ring-4 LDS (round-3 layout/swizzle verbatim).
// ONE barrier per K-tile; frags(t+1) ds_reads drain under MFMA(t) via
// in-order counted lgkmcnt(12); counted vmcnt(4); lead-3 staging.
__global__ __launch_bounds__(512, 2)
void lce_gemm_1ph(const bf16_t* __restrict__ Xb, const bf16_t* __restrict__ Wb,
                  float* __restrict__ pm, float* __restrict__ ps)
{
    __shared__ __align__(16) bf16_t As[4][BM * BK];   // 4 x 16KB
    __shared__ __align__(16) bf16_t Bs[4][BM * BK];   // 4 x 16KB  (128KB total)

    const int bid = blockIdx.x;
    const int wg  = (bid & 7) * (NWG / 8) + (bid >> 3);  // XCD swizzle, bijective
    const int vb  = wg >> 4;       // m-inner: 16 consecutive wgs share a W panel
    const int mb  = wg & 15;
    const int m0  = mb * BM;
    const int v0  = vb * BM;

    const int tid  = threadIdx.x;
    const int lane = tid & 63;
    const int wave = tid >> 6;
    const int wr   = wave >> 2;    // 2(m) x 4(v) wave grid; per-wave 128x64 out
    const int wc   = wave & 3;
    const int lo4  = lane & 15;
    const int hi2  = lane >> 4;

    // read-side swizzled offset (round-3 verified: pair-row layout,
    // byte = (r>>1)*128 + s*16, s = (((r&1)<<2)|g) ^ ((r>>1)&7), g=hi2)
    const int ldsoff = ((lo4 >> 1) << 7)
                     | (((((lo4 & 1) << 2) | hi2) ^ ((lo4 >> 1) & 7)) << 4);

    // staging geometry (inverse swizzle folded into global source address)
    const int l7   = lane & 7, l3 = lane >> 3;
    const int s0   = l7 ^ l3;
    const int srow = (wave << 4) + (l3 << 1) + (s0 >> 2);
    const int scol = (s0 & 3) << 3;
    const bf16_t* baseA = Xb + (size_t)(m0 + srow) * K_DIM + scol;
    const bf16_t* baseB = Wb + (size_t)(v0 + srow) * K_DIM + scol;
    char* ldsA_w = (char*)&As[0][0] + wave * 1024;
    char* ldsB_w = (char*)&Bs[0][0] + wave * 1024;
    const size_t U1 = (size_t)128 * K_DIM;

#define STAGE(tt) do { const int _s = (tt) & 3;                             \
        gll16(baseA + (size_t)(tt) * BK,      ldsA_w + _s * 16384);         \
        gll16(baseA + (size_t)(tt) * BK + U1, ldsA_w + _s * 16384 + 8192);  \
        gll16(baseB + (size_t)(tt) * BK,      ldsB_w + _s * 16384);         \
        gll16(baseB + (size_t)(tt) * BK + U1, ldsB_w + _s * 16384 + 8192);  \
    } while (0)

#define RDFRAG(af_, bv_, tt) do { const int _sl = (tt) & 3;                 \
        const char* _Ab = (const char*)&As[0][0] + _sl * 16384 + ldsoff;    \
        const char* _Bb = (const char*)&Bs[0][0] + _sl * 16384 + ldsoff;    \
        _Pragma("unroll")                                                   \
        for (int m = 0; m < 8; ++m)                                         \
            af_[m] = *(const bf16x8*)(_Ab + (wr * 128 + m * 16) * 64);      \
        _Pragma("unroll")                                                   \
        for (int n = 0; n < 4; ++n)                                         \
            bv_[n] = *(const bf16x8*)(_Bb + (wc * 64 + n * 16) * 64);       \
    } while (0)

#define MFMA32(af_, bv_) do {                                               \
        __builtin_amdgcn_s_setprio(1);                                      \
        _Pragma("unroll")                                                   \
        for (int m = 0; m < 8; ++m)                                         \
            _Pragma("unroll")                                               \
            for (int n = 0; n < 4; ++n)                                     \
                acc[m][n] = __builtin_amdgcn_mfma_f32_16x16x32_bf16(        \
                    af_[m], bv_[n], acc[m][n], 0, 0, 0);                    \
        __builtin_amdgcn_s_setprio(0);                                      \
        __builtin_amdgcn_sched_barrier(0);                                  \
    } while (0)

#define LGKM12 do { asm volatile("s_waitcnt lgkmcnt(12)" ::: "memory");     \
                    __builtin_amdgcn_sched_barrier(0); } while (0)
#define LGKM0  do { asm volatile("s_waitcnt lgkmcnt(0)" ::: "memory");      \
                    __builtin_amdgcn_sched_barrier(0); } while (0)
#define VM4  asm volatile("s_waitcnt vmcnt(4)" ::: "memory")
#define VM0  asm volatile("s_waitcnt vmcnt(0)" ::: "memory")
#define BAR  __builtin_amdgcn_s_barrier()

    f32x4 acc[8][4];
    #pragma unroll
    for (int m = 0; m < 8; ++m)
        #pragma unroll
        for (int n = 0; n < 4; ++n) {
            f32x4 z = {0.f, 0.f, 0.f, 0.f};
            acc[m][n] = z;
        }

    bf16x8 afA[8], bvA[4], afB[8], bvB[4];

    // ---- prologue: stage 0,1,2 (12 issues); tiles 0,1 landed; read frags(0)
    STAGE(0); STAGE(1); STAGE(2);
    VM4;
    BAR;
    RDFRAG(afA, bvA, 0);

    // ---- main loop: tiles 0..59, unroll 2 (static buffer names) ----
    for (int i = 0; i < 30; ++i) {
        const int t = 2 * i;
        STAGE(t + 3);
        RDFRAG(afB, bvB, t + 1);
        LGKM12;                 // frags(t) confirmed (in-order DS)
        MFMA32(afA, bvA);       // tile t
        VM4;                    // tile t+2 landed for next reads
        BAR;

        STAGE(t + 4);
        RDFRAG(afA, bvA, t + 2);
        LGKM12;
        MFMA32(afB, bvB);       // tile t+1
        VM4;
        BAR;
    }
    // ---- peeled tail: tiles 60..63 ----
    STAGE(63);
    RDFRAG(afB, bvB, 61);
    LGKM12; MFMA32(afA, bvA);   // 60
    VM4; BAR;

    RDFRAG(afA, bvA, 62);
    LGKM12; MFMA32(afB, bvB);   // 61
    VM0; BAR;                   // tile 63 landed

    RDFRAG(afB, bvB, 63);
    LGKM12; MFMA32(afA, bvA);   // 62
    BAR;

    LGKM0;  MFMA32(afB, bvB);   // 63

#undef STAGE
#undef RDFRAG
#undef MFMA32
#undef LGKM12
#undef LGKM0
#undef VM4
#undef VM0
#undef BAR

    // ---- epilogue: per-row max/sumexp over this block's 256 cols ----------
    // C layout (m89): col = lane&15, row = (lane>>4)*4 + reg
    float* scrM = (float*)&As[0][0];        // [256][4] wc-partials
    float* scrS = scrM + 1024;
    #pragma unroll
    for (int m = 0; m < 8; ++m) {
        #pragma unroll
        for (int j = 0; j < 4; ++j) {
            float v_[4];
            float vmax = -INFINITY;
            #pragma unroll
            for (int n = 0; n < 4; ++n) {
                const int gcol = v0 + wc * 64 + n * 16 + lo4;
                const float v  = acc[m][n][j];
                v_[n] = (gcol < V_DIM) ? v : -INFINITY;
                vmax = fmaxf(vmax, v_[n]);
            }
            #pragma unroll
            for (int d = 1; d < 16; d <<= 1)
                vmax = fmaxf(vmax, __shfl_xor(vmax, d, 64));
            float s = 0.f;
            if (vmax > -INFINITY) {
                #pragma unroll
                for (int n = 0; n < 4; ++n) s += __expf(v_[n] - vmax);
                #pragma unroll
                for (int d = 1; d < 16; d <<= 1)
                    s += __shfl_xor(s, d, 64);
            }
            if (lo4 == 0) {
                const int row = wr * 128 + m * 16 + hi2 * 4 + j;
                scrM[row * 4 + wc] = vmax;
                scrS[row * 4 + wc] = s;
            }
        }
    }
    __syncthreads();
    if (tid < 256) {
        float M = -INFINITY;
        #pragma unroll
        for (int w4 = 0; w4 < 4; ++w4) M = fmaxf(M, scrM[tid * 4 + w4]);
        float S = 0.f;
        #pragma unroll
        for (int w4 = 0; w4 < 4; ++w4) {
            const float mm = scrM[tid * 4 + w4];
            if (mm > -INFINITY) S += scrS[tid * 4 + w4] * __expf(mm - M);
        }
        const size_t idx = (size_t)vb * M_TOTAL + m0 + tid;
        pm[idx] = M;
        ps[idx] = S;
    }
}

// ---------------- picked logit: one wave per row ---------------------------
__global__ __launch_bounds__(256)
void lce_picked(const bf16_t* __restrict__ Xb, const bf16_t* __restrict__ Wb,
                const int* __restrict__ labels, float* __restrict__ picked)
{
    const int wv  = threadIdx.x >> 6, ln = threadIdx.x & 63;
    const int row = blockIdx.x * 4 + wv;
    const int lbl = labels[row];
    float s = 0.f;
    if (lbl != IGNORE_IDX) {
        const bf16_t* xr = Xb + (size_t)row * K_DIM;
        const bf16_t* wr = Wb + (size_t)lbl * K_DIM;
        #pragma unroll
        for (int c = 0; c < 4; ++c) {
            const bf16x8 a = *(const bf16x8*)(xr + c * 512 + ln * 8);
            const bf16x8 b = *(const bf16x8*)(wr + c * 512 + ln * 8);
            #pragma unroll
            for (int i = 0; i < 8; ++i) s += (float)a[i] * (float)b[i];
        }
    }
    #pragma unroll
    for (int d = 32; d; d >>= 1) s += __shfl_down(s, d, 64);
    if (ln == 0) picked[row] = s;
}

// ---------------- chunk-combine + finalize ---------------------------------
__global__ __launch_bounds__(256)
void lce_row_reduce(const float* __restrict__ pm, const float* __restrict__ ps,
                    const float* __restrict__ picked, const int* __restrict__ labels,
                    float* __restrict__ pb)
{
    const int r   = blockIdx.x * 256 + threadIdx.x;
    const int lbl = labels[r];
    float nll = 0.f, zsq = 0.f, val = 0.f;
    if (lbl != IGNORE_IDX) {
        float M = -INFINITY;
        for (int c = 0; c < NVB; ++c)
            M = fmaxf(M, pm[(size_t)c * M_TOTAL + r]);
        float S = 0.f;
        for (int c = 0; c < NVB; ++c) {
            const float mc = pm[(size_t)c * M_TOTAL + r];
            if (mc > -INFINITY) S += ps[(size_t)c * M_TOTAL + r] * expf(mc - M);
        }
        const float lse = M + logf(S);
        nll = lse - picked[r];
        zsq = lse * lse;
        val = 1.f;
    }
    #pragma unroll
    for (int d = 32; d; d >>= 1) {
        nll += __shfl_down(nll, d, 64);
        zsq += __shfl_down(zsq, d, 64);
        val += __shfl_down(val, d, 64);
    }
    __shared__ float red[3][4];
    const int wv = threadIdx.x >> 6, ln = threadIdx.x & 63;
    if (ln == 0) { red[0][wv] = nll; red[1][wv] = zsq; red[2][wv] = val; }
    __syncthreads();
    if (threadIdx.x == 0) {
        float a = 0.f, b = 0.f, c_ = 0.f;
        #pragma unroll
        for (int i = 0; i < 4; ++i) { a += red[0][i]; b += red[1][i]; c_ += red[2][i]; }
        pb[blockIdx.x * 3 + 0] = a;
        pb[blockIdx.x * 3 + 1] = b;
        pb[blockIdx.x * 3 + 2] = c_;
    }
}

__global__ void lce_finalize(const float* __restrict__ pb, float* __restrict__ out)
{
    float a = 0.f, b = 0.f, c_ = 0.f;
    for (int i = 0; i < 16; ++i) {
        a  += pb[i * 3 + 0];
        b  += pb[i * 3 + 1];
        c_ += pb[i * 3 + 2];
    }
    const float denom = fmaxf(c_, 1.f);
    float loss = a / denom;
    if (c_ > 0.f) loss += Z_REG * (b / denom);
    out[0] = loss;
}

// ---------------- fallback fused fp32 path (round-0 kernel, tiny ws) -------
#define FVC 1024
#define FNCHUNK 50
#define FBK 64
#define LDSPAD 72
__global__ __launch_bounds__(256)
void lce_gemm_stats_fused(const float* __restrict__ X, const float* __restrict__ W,
                          const int* __restrict__ labels,
                          float* __restrict__ pm, float* __restrict__ ps,
                          float* __restrict__ pp)
{
    __shared__ bf16_t As[128][LDSPAD];
    __shared__ bf16_t Bsh[128][LDSPAD];
    __shared__ float  sm[128], ss[128], sp[128];
    __shared__ float  part_m[2][128], part_s[2][128];
    __shared__ int    slab[128];

    const int bx    = blockIdx.x;
    const int chunk = bx >> 5;
    const int mb    = bx & 31;
    const int m0    = mb * 128;
    const int v0    = chunk * FVC;
    const int tid   = threadIdx.x;
    const int lane  = tid & 63;
    const int wave  = tid >> 6;
    const int wr    = wave >> 1;
    const int wc    = wave & 1;
    const int lo4   = lane & 15;
    const int hi2   = lane >> 4;
    const int sr0   = tid >> 4;
    const int sc4   = tid & 15;

    if (tid < 128) {
        sm[tid] = -INFINITY; ss[tid] = 0.f; sp[tid] = 0.f;
        slab[tid] = labels[m0 + tid];
    }
    __syncthreads();

    const int ncols = min(FVC, V_DIM - v0);
    const int nt    = (ncols + 127) >> 7;

    for (int vt = 0; vt < nt; ++vt) {
        f32x4 acc[4][4];
        #pragma unroll
        for (int m = 0; m < 4; ++m)
            #pragma unroll
            for (int n = 0; n < 4; ++n) {
                f32x4 z = {0.f, 0.f, 0.f, 0.f};
                acc[m][n] = z;
            }
        const int vrow0 = v0 + vt * 128;
        for (int kt = 0; kt < K_DIM / FBK; ++kt) {
            #pragma unroll
            for (int i = 0; i < 8; ++i) {
                const int row = i * 16 + sr0;
                const f32x4 va = *(const f32x4*)(X + (size_t)(m0 + row) * K_DIM + kt * FBK + sc4 * 4);
                *(bf16x4*)&As[row][sc4 * 4] = cvt4(va);
                const int grow = vrow0 + row;
                f32x4 vb = {0.f, 0.f, 0.f, 0.f};
                if (grow < V_DIM)
                    vb = *(const f32x4*)(W + (size_t)grow * K_DIM + kt * FBK + sc4 * 4);
                *(bf16x4*)&Bsh[row][sc4 * 4] = cvt4(vb);
            }
            __syncthreads();
            #pragma unroll
            for (int ks = 0; ks < 2; ++ks) {
                bf16x8 af[4], bfr[4];
                #pragma unroll
                for (int m = 0; m < 4; ++m)
                    af[m] = *(const bf16x8*)&As[wr * 64 + m * 16 + lo4][ks * 32 + hi2 * 8];
                #pragma unroll
                for (int n = 0; n < 4; ++n)
                    bfr[n] = *(const bf16x8*)&Bsh[wc * 64 + n * 16 + lo4][ks * 32 + hi2 * 8];
                #pragma unroll
                for (int m = 0; m < 4; ++m)
                    #pragma unroll
                    for (int n = 0; n < 4; ++n)
                        acc[m][n] = __builtin_amdgcn_mfma_f32_16x16x32_bf16(af[m], bfr[n], acc[m][n], 0, 0, 0);
            }
            __syncthreads();
        }
        const int vbase = vrow0 + wc * 64;
        #pragma unroll
        for (int m = 0; m < 4; ++m) {
            #pragma unroll
            for (int j = 0; j < 4; ++j) {
                const int rloc = wr * 64 + m * 16 + hi2 * 4 + j;
                const int lb   = slab[rloc];
                float vmax = -INFINITY;
                float v_[4];
                #pragma unroll
                for (int n = 0; n < 4; ++n) {
                    const int gcol = vbase + n * 16 + lo4;
                    const float v  = acc[m][n][j];
                    const bool ok  = (gcol < V_DIM);
                    v_[n] = ok ? v : -INFINITY;
                    if (ok && gcol == lb) sp[rloc] = v;
                    vmax = fmaxf(vmax, v_[n]);
                }
                #pragma unroll
                for (int d = 1; d < 16; d <<= 1)
                    vmax = fmaxf(vmax, __shfl_xor(vmax, d, 64));
                float s = 0.f;
                #pragma unroll
                for (int n = 0; n < 4; ++n) s += __expf(v_[n] - vmax);
                #pragma unroll
                for (int d = 1; d < 16; d <<= 1) s += __shfl_xor(s, d, 64);
                if (lo4 == 0) { part_m[wc][rloc] = vmax; part_s[wc][rloc] = s; }
            }
        }
        __syncthreads();
        if (tid < 128) {
            const float om  = sm[tid], os = ss[tid];
            const float m0_ = part_m[0][tid], s0 = part_s[0][tid];
            const float m1_ = part_m[1][tid], s1 = part_s[1][tid];
            const float nm  = fmaxf(om, fmaxf(m0_, m1_));
            float ns = 0.f;
            if (om  > -INFINITY) ns += os * __expf(om  - nm);
            if (m0_ > -INFINITY) ns += s0 * __expf(m0_ - nm);
            if (m1_ > -INFINITY) ns += s1 * __expf(m1_ - nm);
            sm[tid] = nm; ss[tid] = ns;
        }
    }
    __syncthreads();
    if (tid < 128) {
        const size_t idx = (size_t)chunk * M_TOTAL + (m0 + tid);
        pm[idx] = sm[tid]; ps[idx] = ss[tid]; pp[idx] = sp[tid];
    }
}

__global__ __launch_bounds__(256)
void lce_row_reduce_f(const float* __restrict__ pm, const float* __restrict__ ps,
                      const float* __restrict__ pp, const int* __restrict__ labels,
                      float* __restrict__ pb)
{
    const int r   = blockIdx.x * 256 + threadIdx.x;
    const int lbl = labels[r];
    float nll = 0.f, zsq = 0.f, val = 0.f;
    if (lbl != IGNORE_IDX) {
        float M = -INFINITY;
        for (int c = 0; c < FNCHUNK; ++c)
            M = fmaxf(M, pm[(size_t)c * M_TOTAL + r]);
        float S = 0.f, P = 0.f;
        for (int c = 0; c < FNCHUNK; ++c) {
            const float mc = pm[(size_t)c * M_TOTAL + r];
            if (mc > -INFINITY) S += ps[(size_t)c * M_TOTAL + r] * expf(mc - M);
            P += pp[(size_t)c * M_TOTAL + r];
        }
        const float lse = M + logf(S);
        nll = lse - P; zsq = lse * lse; val = 1.f;
    }
    #pragma unroll
    for (int d = 32; d; d >>= 1) {
        nll += __shfl_down(nll, d, 64);
        zsq += __shfl_down(zsq, d, 64);
        val += __shfl_down(val, d, 64);
    }
    __shared__ float red[3][4];
    const int wv = threadIdx.x >> 6, ln = threadIdx.x & 63;
    if (ln == 0) { red[0][wv] = nll; red[1][wv] = zsq; red[2][wv] = val; }
    __syncthreads();
    if (threadIdx.x == 0) {
        float a = 0.f, b = 0.f, c_ = 0.f;
        #pragma unroll
        for (int i = 0; i < 4; ++i) { a += red[0][i]; b += red[1][i]; c_ += red[2][i]; }
        pb[blockIdx.x * 3 + 0] = a;
        pb[blockIdx.x * 3 + 1] = b;
        pb[blockIdx.x * 3 + 2] = c_;
    }
}

extern "C" void kernel_launch(void* const* d_in, const int* in_sizes, int n_in,
                              void* d_out, int out_size, void* d_ws, size_t ws_size,
                              hipStream_t stream)
{
    const float* x      = (const float*)d_in[0];
    const int*   labels = (const int*)d_in[1];
    const float* w      = (const float*)d_in[2];
    float*       out    = (float*)d_out;

    const size_t wb_elems = (size_t)V_PAD * K_DIM;      // 103,284,736
    const size_t xb_elems = (size_t)M_TOTAL * K_DIM;    // 8,388,608
    const size_t stat_n   = (size_t)NVB * M_TOTAL;      // 806,912
    const size_t stat_off = wb_elems * 2 + xb_elems * 2;
    const size_t need     = stat_off + stat_n * 2 * sizeof(float)
                          + M_TOTAL * sizeof(float) + 16 * 3 * sizeof(float) + 256;

    if (ws_size >= need) {
        bf16_t* Wb     = (bf16_t*)d_ws;
        bf16_t* Xb     = Wb + wb_elems;
        float*  pm     = (float*)((char*)d_ws + stat_off);
        float*  ps     = pm + stat_n;
        float*  picked = ps + stat_n;
        float*  pb     = picked + M_TOTAL;

        cvt_f32_bf16<<<dim3(4096), dim3(256), 0, stream>>>(
            w, Wb, (long long)(wb_elems / 8), (long long)((size_t)V_DIM * K_DIM / 8));
        cvt_f32_bf16<<<dim3(1024), dim3(256), 0, stream>>>(
            x, Xb, (long long)(xb_elems / 8), (long long)(xb_elems / 8));
        lce_gemm_1ph<<<dim3(NWG), dim3(512), 0, stream>>>(Xb, Wb, pm, ps);
        lce_picked<<<dim3(1024), dim3(256), 0, stream>>>(Xb, Wb, labels, picked);
        lce_row_reduce<<<dim3(16), dim3(256), 0, stream>>>(pm, ps, picked, labels, pb);
        lce_finalize<<<dim3(1), dim3(1), 0, stream>>>(pb, out);
    } else {
        const size_t fstat_n = (size_t)FNCHUNK * M_TOTAL;
        float* pm = (float*)d_ws;
        float* ps = pm + fstat_n;
        float* pp = ps + fstat_n;
        float* pb = pp + fstat_n;
        lce_gemm_stats_fused<<<dim3(FNCHUNK * 32), dim3(256), 0, stream>>>(
            x, w, labels, pm, ps, pp);
        lce_row_reduce_f<<<dim3(16), dim3(256), 0, stream>>>(pm, ps, pp, labels, pb);
        lce_finalize<<<dim3(1), dim3(1), 0, stream>>>(pb, out);
    }
}

// Round 6
// 1051.619 us; speedup vs baseline: 1.3305x; 1.0417x over previous
//
#include <hip/hip_runtime.h>
#include <cmath>
#include <cstdint>

#define M_TOTAL 4096
#define K_DIM   2048
#define V_DIM   50257
#define V_PAD   50432            /* 197*256, zero-padded rows in converted W */
#define NVB     197              /* vocab blocks of 256 */
#define BM 256
#define BK 64
#define NKT (K_DIM / BK)         /* 32 K-steps */
#define NWG (NVB * 16)           /* 3152; 3152/8 = 394 exact */
#define IGNORE_IDX (-100)
#define Z_REG 1e-4f

typedef __bf16 bf16_t;
typedef bf16_t bf16x8 __attribute__((ext_vector_type(8)));
typedef bf16_t bf16x4 __attribute__((ext_vector_type(4)));
typedef float  f32x4  __attribute__((ext_vector_type(4)));

typedef const __attribute__((address_space(1))) void g_cvoid;
typedef __attribute__((address_space(3))) void l_void;

__device__ __forceinline__ void gll16(const void* g, void* l) {
    __builtin_amdgcn_global_load_lds((g_cvoid*)(uintptr_t)g,
                                     (l_void*)(uint32_t)(uintptr_t)l, 16, 0, 0);
}

__device__ inline bf16x4 cvt4(f32x4 v) {
    bf16x4 r;
    r.x = (bf16_t)v.x; r.y = (bf16_t)v.y; r.z = (bf16_t)v.z; r.w = (bf16_t)v.w;
    return r;
}

// ---------------- fp32 -> bf16 convert (pads rows >= valid8 with zeros) ----
__global__ __launch_bounds__(256)
void cvt_f32_bf16(const float* __restrict__ src, bf16_t* __restrict__ dst,
                  long long total8, long long valid8)
{
    const long long stride = (long long)gridDim.x * 256;
    for (long long i = (long long)blockIdx.x * 256 + threadIdx.x; i < total8; i += stride) {
        bf16x8 o;
        if (i < valid8) {
            const float* s = src + i * 8;
            const f32x4 a = *(const f32x4*)s;
            const f32x4 b = *(const f32x4*)(s + 4);
            o[0]=(bf16_t)a.x; o[1]=(bf16_t)a.y; o[2]=(bf16_t)a.z; o[3]=(bf16_t)a.w;
            o[4]=(bf16_t)b.x; o[5]=(bf16_t)b.y; o[6]=(bf16_t)b.z; o[7]=(bf16_t)b.w;
        } else {
            #pragma unroll
            for (int z = 0; z < 8; ++z) o[z] = (bf16_t)0.f;
        }
        *(bf16x8*)(dst + i * 8) = o;
    }
}

// ---------------- 8-phase fused GEMM + online softmax stats ----------------
// m201 schedule port: 256x256, BK=64, dbuf LDS (128KB), 8 waves (2Mx4N),
// 4 quadrant-phases per K-step, 1 half-tile staged per phase (2x gll16),
// counted vmcnt(2) once per K-step, setprio around each 16-MFMA cluster.
// Stage lead = 5 half-tiles; all write-vs-read hazards closed by region
// disjointness + per-phase lgkmcnt(0)+barrier (see ledger in session notes).
__global__ __launch_bounds__(512, 2)
void lce_gemm_8ph(const bf16_t* __restrict__ Xb, const bf16_t* __restrict__ Wb,
                  float* __restrict__ pm, float* __restrict__ ps)
{
    __shared__ __align__(16) bf16_t As[2][BM * BK];   // 2 x 32KB
    __shared__ __align__(16) bf16_t Bs[2][BM * BK];   // 2 x 32KB (128KB total)

    const int bid = blockIdx.x;
    const int wg  = (bid & 7) * (NWG / 8) + (bid >> 3);  // XCD swizzle, bijective
    const int vb  = wg >> 4;       // m-inner: 16 consecutive wgs share a W panel
    const int mb  = wg & 15;
    const int m0  = mb * BM;
    const int v0  = vb * BM;

    const int tid  = threadIdx.x;
    const int lane = tid & 63;
    const int wave = tid >> 6;
    const int wr   = wave >> 2;    // 2(m) x 4(v) wave grid; per-wave 128x64 out
    const int wc   = wave & 3;
    const int lo4  = lane & 15;
    const int hi2  = lane >> 4;

    // ---- read-side swizzle: row r (128B), slot s stored at s^(r&7) ----
    // frag rows = R0 + lo4 with R0 % 8 == 0 -> xor term = lo4&7.
    const int swzK0 = (hi2 ^ (lo4 & 7)) << 4;   // ks=0 slot byte
    const int swzK1 = swzK0 ^ 64;               // ks=1 (slot ^ 4)
    const char* Abase = (const char*)&As[0][0] + (wr * 128 + lo4) * 128;
    const char* Bbase = (const char*)&Bs[0][0] + (wc * 64  + lo4) * 128;

    // ---- staging (inverse swizzle folded into global source col) ----
    const int l7 = lane & 7, l3 = lane >> 3;
    const int scol = ((l7 ^ l3) << 3);          // element offset 0..56
    // A half (mh,c): rows c*128 + mh*64 + wave*8 + l3
    const bf16_t* aSrc = Xb + (size_t)(m0 + wave * 8 + l3) * K_DIM + scol;
    char* aDst = (char*)&As[0][0] + wave * 8 * 128;
    // B half (nh,c): rows c*128 + (wave>>2)*64 + nh*32 + (wave&3)*8 + l3
    const bf16_t* bSrc = Wb + (size_t)(v0 + (wave >> 2) * 64 + (wave & 3) * 8 + l3) * K_DIM + scol;
    char* bDst = (char*)&Bs[0][0] + ((wave >> 2) * 64 + (wave & 3) * 8) * 128;

#define STAGE_A(s, mh) do { const int _b = ((s) & 1) * 32768;               \
        gll16(aSrc + (size_t)((mh) * 64)       * K_DIM + (s) * BK,          \
              aDst + _b + ((mh) * 64)       * 128);                         \
        gll16(aSrc + (size_t)(128 + (mh) * 64) * K_DIM + (s) * BK,          \
              aDst + _b + (128 + (mh) * 64) * 128);                         \
    } while (0)
#define STAGE_B(s, nh) do { const int _b = ((s) & 1) * 32768;               \
        gll16(bSrc + (size_t)((nh) * 32)       * K_DIM + (s) * BK,          \
              bDst + _b + ((nh) * 32)       * 128);                         \
        gll16(bSrc + (size_t)(128 + (nh) * 32) * K_DIM + (s) * BK,          \
              bDst + _b + (128 + (nh) * 32) * 128);                         \
    } while (0)

#define RD_A(mh, ab) do {                                                   \
        _Pragma("unroll")                                                   \
        for (int ks = 0; ks < 2; ++ks)                                      \
            _Pragma("unroll")                                               \
            for (int m = 0; m < 4; ++m)                                     \
                afH[ks * 4 + m] = *(const bf16x8*)(Abase + (ab)             \
                    + ((mh) * 64 + m * 16) * 128 + (ks ? swzK1 : swzK0));   \
    } while (0)
#define RD_B(arr, nh, ab) do {                                              \
        _Pragma("unroll")                                                   \
        for (int ks = 0; ks < 2; ++ks)                                      \
            _Pragma("unroll")                                               \
            for (int n = 0; n < 2; ++n)                                     \
                arr[ks * 2 + n] = *(const bf16x8*)(Bbase + (ab)             \
                    + (((nh) * 2 + n) * 16) * 128 + (ks ? swzK1 : swzK0));  \
    } while (0)

#define MF16(mh, nh, bArr) do {                                             \
        __builtin_amdgcn_s_setprio(1);                                      \
        _Pragma("unroll")                                                   \
        for (int ks = 0; ks < 2; ++ks)                                      \
            _Pragma("unroll")                                               \
            for (int m = 0; m < 4; ++m)                                     \
                _Pragma("unroll")                                           \
                for (int n = 0; n < 2; ++n)                                 \
                    acc[(mh) * 4 + m][(nh) * 2 + n] =                       \
                        __builtin_amdgcn_mfma_f32_16x16x32_bf16(            \
                            afH[ks * 4 + m], bArr[ks * 2 + n],              \
                            acc[(mh) * 4 + m][(nh) * 2 + n], 0, 0, 0);      \
        __builtin_amdgcn_s_setprio(0);                                      \
    } while (0)

#define SB   __builtin_amdgcn_sched_barrier(0)
#define BAR  __builtin_amdgcn_s_barrier()
#define LGK0 do { asm volatile("s_waitcnt lgkmcnt(0)" ::: "memory"); SB; } while (0)
#define VM2  do { asm volatile("s_waitcnt vmcnt(2)" ::: "memory"); SB; } while (0)
#define VM0  do { asm volatile("s_waitcnt vmcnt(0)" ::: "memory"); SB; } while (0)

    f32x4 acc[8][4];
    #pragma unroll
    for (int m = 0; m < 8; ++m)
        #pragma unroll
        for (int n = 0; n < 4; ++n) {
            f32x4 z = {0.f, 0.f, 0.f, 0.f};
            acc[m][n] = z;
        }

    bf16x8 afH[8], b0[4], b1[4];

    // ---- prologue: half-tiles A0(0),B0(0),B1(0),A1(0),A0(1) (10 loads);
    //      vmcnt(2) leaves only A0(1) in flight -> K-step 0 fully landed.
    STAGE_A(0, 0); STAGE_B(0, 0); STAGE_B(0, 1); STAGE_A(0, 1); STAGE_A(1, 0);
    VM2;
    BAR;

    for (int t = 0; t < NKT; ++t) {
        const int ab = (t & 1) << 15;

        // ===== ph0 (mh0,nh0): read A0(8)+B0(4); stage B0(t+1) =====
        RD_A(0, ab);
        RD_B(b0, 0, ab);
        if (t + 1 < NKT) STAGE_B(t + 1, 0);
        SB; BAR;
        LGK0;
        MF16(0, 0, b0);
        SB; BAR;

        // ===== ph1 (mh0,nh1): read B1(4); stage B1(t+1) =====
        RD_B(b1, 1, ab);
        if (t + 1 < NKT) STAGE_B(t + 1, 1);
        SB; BAR;
        LGK0;
        MF16(0, 1, b1);
        SB; BAR;

        // ===== ph2 (mh1,nh1): read A1(8); stage A1(t+1) =====
        RD_A(1, ab);
        if (t + 1 < NKT) STAGE_A(t + 1, 1);
        SB; BAR;
        LGK0;
        MF16(1, 1, b1);
        SB; BAR;

        // ===== ph3 (mh1,nh0): no reads; stage A0(t+2); counted vmcnt =====
        if (t + 2 < NKT) STAGE_A(t + 2, 0);
        SB; BAR;
        MF16(1, 0, b0);
        SB;
        if (t < NKT - 2)       VM2;   // leaves only A0(t+2) in flight
        else if (t == NKT - 2) VM0;   // drain: K-step NKT-1 fully landed
        BAR;
    }

#undef STAGE_A
#undef STAGE_B
#undef RD_A
#undef RD_B
#undef MF16
#undef SB
#undef BAR
#undef LGK0
#undef VM2
#undef VM0

    // ---- epilogue: per-row max/sumexp over this block's 256 cols ----------
    // C layout (m89): col = lane&15, row = (lane>>4)*4 + reg
    float* scrM = (float*)&As[0][0];        // [256][4] wc-partials
    float* scrS = scrM + 1024;
    #pragma unroll
    for (int m = 0; m < 8; ++m) {
        #pragma unroll
        for (int j = 0; j < 4; ++j) {
            float v_[4];
            float vmax = -INFINITY;
            #pragma unroll
            for (int n = 0; n < 4; ++n) {
                const int gcol = v0 + wc * 64 + n * 16 + lo4;
                const float v  = acc[m][n][j];
                v_[n] = (gcol < V_DIM) ? v : -INFINITY;
                vmax = fmaxf(vmax, v_[n]);
            }
            #pragma unroll
            for (int d = 1; d < 16; d <<= 1)
                vmax = fmaxf(vmax, __shfl_xor(vmax, d, 64));
            float s = 0.f;
            if (vmax > -INFINITY) {
                #pragma unroll
                for (int n = 0; n < 4; ++n) s += __expf(v_[n] - vmax);
                #pragma unroll
                for (int d = 1; d < 16; d <<= 1)
                    s += __shfl_xor(s, d, 64);
            }
            if (lo4 == 0) {
                const int row = wr * 128 + m * 16 + hi2 * 4 + j;
                scrM[row * 4 + wc] = vmax;
                scrS[row * 4 + wc] = s;
            }
        }
    }
    __syncthreads();
    if (tid < 256) {
        float M = -INFINITY;
        #pragma unroll
        for (int w4 = 0; w4 < 4; ++w4) M = fmaxf(M, scrM[tid * 4 + w4]);
        float S = 0.f;
        #pragma unroll
        for (int w4 = 0; w4 < 4; ++w4) {
            const float mm = scrM[tid * 4 + w4];
            if (mm > -INFINITY) S += scrS[tid * 4 + w4] * __expf(mm - M);
        }
        const size_t idx = (size_t)vb * M_TOTAL + m0 + tid;
        pm[idx] = M;
        ps[idx] = S;
    }
}

// ---------------- picked logit: one wave per row ---------------------------
__global__ __launch_bounds__(256)
void lce_picked(const bf16_t* __restrict__ Xb, const bf16_t* __restrict__ Wb,
                const int* __restrict__ labels, float* __restrict__ picked)
{
    const int wv  = threadIdx.x >> 6, ln = threadIdx.x & 63;
    const int row = blockIdx.x * 4 + wv;
    const int lbl = labels[row];
    float s = 0.f;
    if (lbl != IGNORE_IDX) {
        const bf16_t* xr = Xb + (size_t)row * K_DIM;
        const bf16_t* wr = Wb + (size_t)lbl * K_DIM;
        #pragma unroll
        for (int c = 0; c < 4; ++c) {
            const bf16x8 a = *(const bf16x8*)(xr + c * 512 + ln * 8);
            const bf16x8 b = *(const bf16x8*)(wr + c * 512 + ln * 8);
            #pragma unroll
            for (int i = 0; i < 8; ++i) s += (float)a[i] * (float)b[i];
        }
    }
    #pragma unroll
    for (int d = 32; d; d >>= 1) s += __shfl_down(s, d, 64);
    if (ln == 0) picked[row] = s;
}

// ---------------- chunk-combine + finalize ---------------------------------
__global__ __launch_bounds__(256)
void lce_row_reduce(const float* __restrict__ pm, const float* __restrict__ ps,
                    const float* __restrict__ picked, const int* __restrict__ labels,
                    float* __restrict__ pb)
{
    const int r   = blockIdx.x * 256 + threadIdx.x;
    const int lbl = labels[r];
    float nll = 0.f, zsq = 0.f, val = 0.f;
    if (lbl != IGNORE_IDX) {
        float M = -INFINITY;
        for (int c = 0; c < NVB; ++c)
            M = fmaxf(M, pm[(size_t)c * M_TOTAL + r]);
        float S = 0.f;
        for (int c = 0; c < NVB; ++c) {
            const float mc = pm[(size_t)c * M_TOTAL + r];
            if (mc > -INFINITY) S += ps[(size_t)c * M_TOTAL + r] * expf(mc - M);
        }
        const float lse = M + logf(S);
        nll = lse - picked[r];
        zsq = lse * lse;
        val = 1.f;
    }
    #pragma unroll
    for (int d = 32; d; d >>= 1) {
        nll += __shfl_down(nll, d, 64);
        zsq += __shfl_down(zsq, d, 64);
        val += __shfl_down(val, d, 64);
    }
    __shared__ float red[3][4];
    const int wv = threadIdx.x >> 6, ln = threadIdx.x & 63;
    if (ln == 0) { red[0][wv] = nll; red[1][wv] = zsq; red[2][wv] = val; }
    __syncthreads();
    if (threadIdx.x == 0) {
        float a = 0.f, b = 0.f, c_ = 0.f;
        #pragma unroll
        for (int i = 0; i < 4; ++i) { a += red[0][i]; b += red[1][i]; c_ += red[2][i]; }
        pb[blockIdx.x * 3 + 0] = a;
        pb[blockIdx.x * 3 + 1] = b;
        pb[blockIdx.x * 3 + 2] = c_;
    }
}

__global__ void lce_finalize(const float* __restrict__ pb, float* __restrict__ out)
{
    float a = 0.f, b = 0.f, c_ = 0.f;
    for (int i = 0; i < 16; ++i) {
        a  += pb[i * 3 + 0];
        b  += pb[i * 3 + 1];
        c_ += pb[i * 3 + 2];
    }
    const float denom = fmaxf(c_, 1.f);
    float loss = a / denom;
    if (c_ > 0.f) loss += Z_REG * (b / denom);
    out[0] = loss;
}

// ---------------- fallback fused fp32 path (round-0 kernel, tiny ws) -------
#define FVC 1024
#define FNCHUNK 50
#define FBK 64
#define LDSPAD 72
__global__ __launch_bounds__(256)
void lce_gemm_stats_fused(const float* __restrict__ X, const float* __restrict__ W,
                          const int* __restrict__ labels,
                          float* __restrict__ pm, float* __restrict__ ps,
                          float* __restrict__ pp)
{
    __shared__ bf16_t As[128][LDSPAD];
    __shared__ bf16_t Bsh[128][LDSPAD];
    __shared__ float  sm[128], ss[128], sp[128];
    __shared__ float  part_m[2][128], part_s[2][128];
    __shared__ int    slab[128];

    const int bx    = blockIdx.x;
    const int chunk = bx >> 5;
    const int mb    = bx & 31;
    const int m0    = mb * 128;
    const int v0    = chunk * FVC;
    const int tid   = threadIdx.x;
    const int lane  = tid & 63;
    const int wave  = tid >> 6;
    const int wr    = wave >> 1;
    const int wc    = wave & 1;
    const int lo4   = lane & 15;
    const int hi2   = lane >> 4;
    const int sr0   = tid >> 4;
    const int sc4   = tid & 15;

    if (tid < 128) {
        sm[tid] = -INFINITY; ss[tid] = 0.f; sp[tid] = 0.f;
        slab[tid] = labels[m0 + tid];
    }
    __syncthreads();

    const int ncols = min(FVC, V_DIM - v0);
    const int nt    = (ncols + 127) >> 7;

    for (int vt = 0; vt < nt; ++vt) {
        f32x4 acc[4][4];
        #pragma unroll
        for (int m = 0; m < 4; ++m)
            #pragma unroll
            for (int n = 0; n < 4; ++n) {
                f32x4 z = {0.f, 0.f, 0.f, 0.f};
                acc[m][n] = z;
            }
        const int vrow0 = v0 + vt * 128;
        for (int kt = 0; kt < K_DIM / FBK; ++kt) {
            #pragma unroll
            for (int i = 0; i < 8; ++i) {
                const int row = i * 16 + sr0;
                const f32x4 va = *(const f32x4*)(X + (size_t)(m0 + row) * K_DIM + kt * FBK + sc4 * 4);
                *(bf16x4*)&As[row][sc4 * 4] = cvt4(va);
                const int grow = vrow0 + row;
                f32x4 vb = {0.f, 0.f, 0.f, 0.f};
                if (grow < V_DIM)
                    vb = *(const f32x4*)(W + (size_t)grow * K_DIM + kt * FBK + sc4 * 4);
                *(bf16x4*)&Bsh[row][sc4 * 4] = cvt4(vb);
            }
            __syncthreads();
            #pragma unroll
            for (int ks = 0; ks < 2; ++ks) {
                bf16x8 af[4], bfr[4];
                #pragma unroll
                for (int m = 0; m < 4; ++m)
                    af[m] = *(const bf16x8*)&As[wr * 64 + m * 16 + lo4][ks * 32 + hi2 * 8];
                #pragma unroll
                for (int n = 0; n < 4; ++n)
                    bfr[n] = *(const bf16x8*)&Bsh[wc * 64 + n * 16 + lo4][ks * 32 + hi2 * 8];
                #pragma unroll
                for (int m = 0; m < 4; ++m)
                    #pragma unroll
                    for (int n = 0; n < 4; ++n)
                        acc[m][n] = __builtin_amdgcn_mfma_f32_16x16x32_bf16(af[m], bfr[n], acc[m][n], 0, 0, 0);
            }
            __syncthreads();
        }
        const int vbase = vrow0 + wc * 64;
        #pragma unroll
        for (int m = 0; m < 4; ++m) {
            #pragma unroll
            for (int j = 0; j < 4; ++j) {
                const int rloc = wr * 64 + m * 16 + hi2 * 4 + j;
                const int lb   = slab[rloc];
                float vmax = -INFINITY;
                float v_[4];
                #pragma unroll
                for (int n = 0; n < 4; ++n) {
                    const int gcol = vbase + n * 16 + lo4;
                    const float v  = acc[m][n][j];
                    const bool ok  = (gcol < V_DIM);
                    v_[n] = ok ? v : -INFINITY;
                    if (ok && gcol == lb) sp[rloc] = v;
                    vmax = fmaxf(vmax, v_[n]);
                }
                #pragma unroll
                for (int d = 1; d < 16; d <<= 1)
                    vmax = fmaxf(vmax, __shfl_xor(vmax, d, 64));
                float s = 0.f;
                #pragma unroll
                for (int n = 0; n < 4; ++n) s += __expf(v_[n] - vmax);
                #pragma unroll
                for (int d = 1; d < 16; d <<= 1) s += __shfl_xor(s, d, 64);
                if (lo4 == 0) { part_m[wc][rloc] = vmax; part_s[wc][rloc] = s; }
            }
        }
        __syncthreads();
        if (tid < 128) {
            const float om  = sm[tid], os = ss[tid];
            const float m0_ = part_m[0][tid], s0 = part_s[0][tid];
            const float m1_ = part_m[1][tid], s1 = part_s[1][tid];
            const float nm  = fmaxf(om, fmaxf(m0_, m1_));
            float ns = 0.f;
            if (om  > -INFINITY) ns += os * __expf(om  - nm);
            if (m0_ > -INFINITY) ns += s0 * __expf(m0_ - nm);
            if (m1_ > -INFINITY) ns += s1 * __expf(m1_ - nm);
            sm[tid] = nm; ss[tid] = ns;
        }
    }
    __syncthreads();
    if (tid < 128) {
        const size_t idx = (size_t)chunk * M_TOTAL + (m0 + tid);
        pm[idx] = sm[tid]; ss[tid] = ss[tid];
        pm[idx] = sm[tid]; ps[idx] = ss[tid]; pp[idx] = sp[tid];
    }
}

__global__ __launch_bounds__(256)
void lce_row_reduce_f(const float* __restrict__ pm, const float* __restrict__ ps,
                      const float* __restrict__ pp, const int* __restrict__ labels,
                      float* __restrict__ pb)
{
    const int r   = blockIdx.x * 256 + threadIdx.x;
    const int lbl = labels[r];
    float nll = 0.f, zsq = 0.f, val = 0.f;
    if (lbl != IGNORE_IDX) {
        float M = -INFINITY;
        for (int c = 0; c < FNCHUNK; ++c)
            M = fmaxf(M, pm[(size_t)c * M_TOTAL + r]);
        float S = 0.f, P = 0.f;
        for (int c = 0; c < FNCHUNK; ++c) {
            const float mc = pm[(size_t)c * M_TOTAL + r];
            if (mc > -INFINITY) S += ps[(size_t)c * M_TOTAL + r] * expf(mc - M);
            P += pp[(size_t)c * M_TOTAL + r];
        }
        const float lse = M + logf(S);
        nll = lse - P; zsq = lse * lse; val = 1.f;
    }
    #pragma unroll
    for (int d = 32; d; d >>= 1) {
        nll += __shfl_down(nll, d, 64);
        zsq += __shfl_down(zsq, d, 64);
        val += __shfl_down(val, d, 64);
    }
    __shared__ float red[3][4];
    const int wv = threadIdx.x >> 6, ln = threadIdx.x & 63;
    if (ln == 0) { red[0][wv] = nll; red[1][wv] = zsq; red[2][wv] = val; }
    __syncthreads();
    if (threadIdx.x == 0) {
        float a = 0.f, b = 0.f, c_ = 0.f;
        #pragma unroll
        for (int i = 0; i < 4; ++i) { a += red[0][i]; b += red[1][i]; c_ += red[2][i]; }
        pb[blockIdx.x * 3 + 0] = a;
        pb[blockIdx.x * 3 + 1] = b;
        pb[blockIdx.x * 3 + 2] = c_;
    }
}

extern "C" void kernel_launch(void* const* d_in, const int* in_sizes, int n_in,
                              void* d_out, int out_size, void* d_ws, size_t ws_size,
                              hipStream_t stream)
{
    const float* x      = (const float*)d_in[0];
    const int*   labels = (const int*)d_in[1];
    const float* w      = (const float*)d_in[2];
    float*       out    = (float*)d_out;

    const size_t wb_elems = (size_t)V_PAD * K_DIM;      // 103,284,736
    const size_t xb_elems = (size_t)M_TOTAL * K_DIM;    // 8,388,608
    const size_t stat_n   = (size_t)NVB * M_TOTAL;      // 806,912
    const size_t stat_off = wb_elems * 2 + xb_elems * 2;
    const size_t need     = stat_off + stat_n * 2 * sizeof(float)
                          + M_TOTAL * sizeof(float) + 16 * 3 * sizeof(float) + 256;

    if (ws_size >= need) {
        bf16_t* Wb     = (bf16_t*)d_ws;
        bf16_t* Xb     = Wb + wb_elems;
        float*  pm     = (float*)((char*)d_ws + stat_off);
        float*  ps     = pm + stat_n;
        float*  picked = ps + stat_n;
        float*  pb     = picked + M_TOTAL;

        cvt_f32_bf16<<<dim3(4096), dim3(256), 0, stream>>>(
            w, Wb, (long long)(wb_elems / 8), (long long)((size_t)V_DIM * K_DIM / 8));
        cvt_f32_bf16<<<dim3(1024), dim3(256), 0, stream>>>(
            x, Xb, (long long)(xb_elems / 8), (long long)(xb_elems / 8));
        lce_gemm_8ph<<<dim3(NWG), dim3(512), 0, stream>>>(Xb, Wb, pm, ps);
        lce_picked<<<dim3(1024), dim3(256), 0, stream>>>(Xb, Wb, labels, picked);
        lce_row_reduce<<<dim3(16), dim3(256), 0, stream>>>(pm, ps, picked, labels, pb);
        lce_finalize<<<dim3(1), dim3(1), 0, stream>>>(pb, out);
    } else {
        const size_t fstat_n = (size_t)FNCHUNK * M_TOTAL;
        float* pm = (float*)d_ws;
        float* ps = pm + fstat_n;
        float* pp = ps + fstat_n;
        float* pb = pp + fstat_n;
        lce_gemm_stats_fused<<<dim3(FNCHUNK * 32), dim3(256), 0, stream>>>(
            x, w, labels, pm, ps, pp);
        lce_row_reduce_f<<<dim3(16), dim3(256), 0, stream>>>(pm, ps, pp, labels, pb);
        lce_finalize<<<dim3(1), dim3(1), 0, stream>>>(pb, out);
    }
}